// Round 2
// baseline (163.833 us; speedup 1.0000x reference)
//
#include <hip/hip_runtime.h>
#include <math.h>

// Sizes (fixed by the reference problem)
#define BSZ 64
#define DV  1024
#define NQ  32
#define NS  1024
#define DD  128

#define ALPHA 0.5f

typedef __attribute__((ext_vector_type(8))) int   int8v;    // 32B fp8 MFMA A/B frag (8 VGPR)
typedef __attribute__((ext_vector_type(4))) float floatx4;  // MFMA C/D frag
#define SCALE1 127      // e8m0 byte 0x7F = 2^0 = 1.0

// ==================== fused kernel ====================
// blocks 0..1023 : multi-vector max-sim scores. Block = (bg of 4 b's, c).
//   REGISTER BUDGET (the round-1 lesson): af[4][2]=64 VGPR + mx=32 + rawA/B=64
//   + bf=8 + temps ~= 200 < 256 @ 2 waves/SIMD. 8-b blocks need 128 VGPR of
//   A-frags alone -> spill -> 5x slowdown (measured: VGPR_Count=128, 78us).
//   Phase A: convert this bg's q rows fp32->fp8 into LDS (8 chunks), once.
//   Phase B: stream d_multi[c] fp32 from L2 (XCD swizzle keeps the 4MB slice
//   resident), convert to fp8 in regs (bit-identical to verified prep bytes),
//   8 mfma_scale (4 b x 2 nt) per st-tile, running per-lane fmax.
//   d L2 traffic: 1024 blocks x 512KB = 536MB ~ 15.5us -> L2-BW-bound.
// blocks 1024..1087: single-vector CE loss rows (exact fp32, unchanged math).
__launch_bounds__(256, 2)
__global__ void fused_kernel(const float* __restrict__ qm, const float* __restrict__ dm,
                             const float* __restrict__ qs, const float* __restrict__ ds,
                             float* __restrict__ scores, float* __restrict__ svrow) {
    __shared__ __align__(32) unsigned char lds_q[8 * 2048];  // 16 KB fp8 A-chunks
    __shared__ float lds_smax[4][4][32];                     // 2 KB
    __shared__ float row[BSZ];

    int bid = blockIdx.x;
    int t = threadIdx.x;

    if (bid >= 1024) {
        // ---- single-vector CE loss rows (verbatim from verified prep) ----
        int b = bid - 1024;
        int c = t >> 2, part = t & 3;
        const float4* qv = (const float4*)(qs + b * DV);
        const float4* dv = (const float4*)(ds + c * DV);
        float acc = 0.f;
        int k0 = part * 64;
#pragma unroll 8
        for (int k = k0; k < k0 + 64; ++k) {
            float4 a = qv[k], bb = dv[k];
            acc += a.x * bb.x + a.y * bb.y + a.z * bb.z + a.w * bb.w;
        }
        acc += __shfl_xor(acc, 1);
        acc += __shfl_xor(acc, 2);
        if (part == 0) row[c] = acc;
        __syncthreads();
        if (t < BSZ) {
            float v = row[t];
            float m = v;
#pragma unroll
            for (int o = 1; o < 64; o <<= 1) m = fmaxf(m, __shfl_xor(m, o));
            float e = expf(v - m);
#pragma unroll
            for (int o = 1; o < 64; o <<= 1) e += __shfl_xor(e, o);
            float lse = m + logf(e);
            if (t == 0) svrow[b] = lse - row[b];
        }
        return;
    }

    // ---- multi-vector path ----
    int x = bid & 7, rr = bid >> 3;
    int c  = x * 8 + (rr & 7);     // XCD x keeps c in [8x,8x+8): 4MB fp32 slice L2-resident
    int bg = rr >> 3;              // 0..15 -> query rows b = bg*4 .. bg*4+3
    int w = t >> 6, l = t & 63;
    int lane16 = l & 15, quad = (l >> 4) & 3;

    // Phase A: q fp32 -> fp8 chunks in LDS. Wave w converts chunks 2w, 2w+1.
    // Chunk ch = bi*2+nt: lane l holds q[bg*4+bi][nt*16+(l&15)][quad*32 .. +32] (32B).
#pragma unroll
    for (int k = 0; k < 2; ++k) {
        int ch = w * 2 + k;
        int bi = ch >> 1, nt = ch & 1;
        const float* src = qm + ((size_t)((bg * 4 + bi) * NQ + nt * 16 + lane16)) * DD + quad * 32;
        int dw[8];
#pragma unroll
        for (int j = 0; j < 8; ++j) {
            float4 v = ((const float4*)src)[j];
            int d0 = __builtin_amdgcn_cvt_pk_fp8_f32(v.x, v.y, 0, false);
            dw[j]  = __builtin_amdgcn_cvt_pk_fp8_f32(v.z, v.w, d0, true);
        }
        int4* dst = (int4*)(lds_q + ch * 2048 + l * 32);
        dst[0] = make_int4(dw[0], dw[1], dw[2], dw[3]);
        dst[1] = make_int4(dw[4], dw[5], dw[6], dw[7]);
    }
    __syncthreads();

    // Every wave pulls all 8 A-frags into registers (64 VGPR, one-time LDS read).
    int8v af[4][2];
#pragma unroll
    for (int bi = 0; bi < 4; ++bi)
#pragma unroll
        for (int nt = 0; nt < 2; ++nt)
            af[bi][nt] = *(const int8v*)(lds_q + (bi * 2 + nt) * 2048 + l * 32);

    float mx[4][2][4];
#pragma unroll
    for (int bi = 0; bi < 4; ++bi)
#pragma unroll
        for (int nt = 0; nt < 2; ++nt)
#pragma unroll
            for (int r = 0; r < 4; ++r) mx[bi][nt][r] = -1e30f;

    // Phase B: wave w owns st = w + 4i (same map as the verified kernel).
    // True double buffer (rawA/rawB are NAMED so no runtime-indexed arrays;
    // #pragma unroll 1 so the compiler can't hoist all 16 tile loads).
    const float* base = dm + ((size_t)(c * NS + w * 16 + lane16)) * DD + quad * 32;
    const size_t STEP = (size_t)4 * 16 * DD;  // 4 st-tiles of floats

    float4 rawA[8], rawB[8];
#pragma unroll
    for (int j = 0; j < 8; ++j) rawA[j] = ((const float4*)(base))[j];
#pragma unroll
    for (int j = 0; j < 8; ++j) rawB[j] = ((const float4*)(base + STEP))[j];

#pragma unroll 1
    for (int i = 0; i < 16; i += 2) {
        // ---- tile i (rawA): convert, prefetch i+2 into rawA, 8 MFMAs ----
        int8v bfA;
#pragma unroll
        for (int j = 0; j < 8; ++j) {
            int d0 = __builtin_amdgcn_cvt_pk_fp8_f32(rawA[j].x, rawA[j].y, 0, false);
            bfA[j] = __builtin_amdgcn_cvt_pk_fp8_f32(rawA[j].z, rawA[j].w, d0, true);
        }
        if (i + 2 < 16) {
            const float* p = base + (size_t)(i + 2) * STEP;
#pragma unroll
            for (int j = 0; j < 8; ++j) rawA[j] = ((const float4*)p)[j];
        }
#pragma unroll
        for (int bi = 0; bi < 4; ++bi)
#pragma unroll
            for (int nt = 0; nt < 2; ++nt) {
                floatx4 acc = __builtin_amdgcn_mfma_scale_f32_16x16x128_f8f6f4(
                    af[bi][nt], bfA, (floatx4){0.f, 0.f, 0.f, 0.f},
                    0, 0, 0, SCALE1, 0, SCALE1);
#pragma unroll
                for (int r = 0; r < 4; ++r)
                    mx[bi][nt][r] = fmaxf(mx[bi][nt][r], acc[r]);
            }

        // ---- tile i+1 (rawB): convert, prefetch i+3 into rawB, 8 MFMAs ----
        int8v bfB;
#pragma unroll
        for (int j = 0; j < 8; ++j) {
            int d0 = __builtin_amdgcn_cvt_pk_fp8_f32(rawB[j].x, rawB[j].y, 0, false);
            bfB[j] = __builtin_amdgcn_cvt_pk_fp8_f32(rawB[j].z, rawB[j].w, d0, true);
        }
        if (i + 3 < 16) {
            const float* p = base + (size_t)(i + 3) * STEP;
#pragma unroll
            for (int j = 0; j < 8; ++j) rawB[j] = ((const float4*)p)[j];
        }
#pragma unroll
        for (int bi = 0; bi < 4; ++bi)
#pragma unroll
            for (int nt = 0; nt < 2; ++nt) {
                floatx4 acc = __builtin_amdgcn_mfma_scale_f32_16x16x128_f8f6f4(
                    af[bi][nt], bfB, (floatx4){0.f, 0.f, 0.f, 0.f},
                    0, 0, 0, SCALE1, 0, SCALE1);
#pragma unroll
                for (int r = 0; r < 4; ++r)
                    mx[bi][nt][r] = fmaxf(mx[bi][nt][r], acc[r]);
            }
    }

    // ---- end-of-kernel reduction (verified scheme) ----
#pragma unroll
    for (int bi = 0; bi < 4; ++bi)
#pragma unroll
        for (int nt = 0; nt < 2; ++nt)
#pragma unroll
            for (int r = 0; r < 4; ++r) {
                float v = mx[bi][nt][r];
                v = fmaxf(v, __shfl_xor(v, 1));
                v = fmaxf(v, __shfl_xor(v, 2));
                v = fmaxf(v, __shfl_xor(v, 4));
                v = fmaxf(v, __shfl_xor(v, 8));
                mx[bi][nt][r] = v;
            }
    if (lane16 == 0) {
#pragma unroll
        for (int bi = 0; bi < 4; ++bi)
#pragma unroll
            for (int nt = 0; nt < 2; ++nt)
#pragma unroll
                for (int r = 0; r < 4; ++r)
                    lds_smax[w][bi][nt * 16 + quad * 4 + r] = mx[bi][nt][r];
    }
    __syncthreads();
    if (t < 4 * NQ) {
        int bi = t >> 5, n = t & 31;
        float v = fmaxf(fmaxf(lds_smax[0][bi][n], lds_smax[1][bi][n]),
                        fmaxf(lds_smax[2][bi][n], lds_smax[3][bi][n]));
#pragma unroll
        for (int o = 1; o < 32; o <<= 1) v += __shfl_xor(v, o);
        if (n == 0) scores[(bg * 4 + bi) * BSZ + c] = v;
    }
}

// ==================== finisher ====================
__global__ void finish_kernel(const float* __restrict__ scores, const float* __restrict__ svrow,
                              float* __restrict__ out) {
    int t = threadIdx.x;  // 64
    float pos = scores[t * BSZ + t];
    float neg = -1e30f;
    for (int cc = 0; cc < BSZ; ++cc)
        if (cc != t) neg = fmaxf(neg, scores[t * BSZ + cc]);
    float xx = neg - pos;
    float sp = fmaxf(xx, 0.f) + log1pf(expf(-fabsf(xx)));   // stable softplus
    float sv = svrow[t];
#pragma unroll
    for (int o = 1; o < 64; o <<= 1) {
        sp += __shfl_xor(sp, o);
        sv += __shfl_xor(sv, o);
    }
    if (t == 0) out[0] = ALPHA * sv + (1.0f - ALPHA) * (sp * (1.0f / BSZ));
}

// ==================== launch ====================
extern "C" void kernel_launch(void* const* d_in, const int* in_sizes, int n_in,
                              void* d_out, int out_size, void* d_ws, size_t ws_size,
                              hipStream_t stream) {
    const float* q_single = (const float*)d_in[0];
    const float* d_single = (const float*)d_in[1];
    const float* q_multi  = (const float*)d_in[2];
    const float* d_multi  = (const float*)d_in[3];
    float* out = (float*)d_out;

    // ws: scores 16KB | svrow 256B
    float* scores = (float*)d_ws;
    float* svrow  = (float*)((char*)d_ws + 16384);

    fused_kernel<<<1088, 256, 0, stream>>>(q_multi, d_multi, q_single, d_single,
                                           scores, svrow);
    finish_kernel<<<1, 64, 0, stream>>>(scores, svrow, out);
}

// Round 3
// 139.790 us; speedup vs baseline: 1.1720x; 1.1720x over previous
//
#include <hip/hip_runtime.h>
#include <math.h>

// Sizes (fixed by the reference problem)
#define BSZ 64
#define DV  1024
#define NQ  32
#define NS  1024
#define DD  128

#define ALPHA 0.5f

typedef __attribute__((ext_vector_type(8))) int   int8v;    // 32B fp8 MFMA A/B frag (8 VGPR)
typedef __attribute__((ext_vector_type(4))) float floatx4;  // MFMA C/D frag
#define SCALE1 127      // e8m0 byte 0x7F = 2^0 = 1.0

// ==================== fused kernel ====================
// blocks 0..63   : single-vector CE loss rows (dispatched first -> free CUs fast).
// blocks 64..319 : multi-vector max-sim. Block = (bg of 16 b's, c); 8 waves,
//   wave w owns b's {bg*16+2w, +1} (af[2][2]=32 VGPR, mx=16 -> no pressure).
//   d-tile pipeline (round-2 lesson: register-held prefetch gets sunk by the
//   compiler -> serialized latency; so pipeline through LDS + raw s_barrier):
//     - 16-slot LDS ring of 2KB fp8 d-tiles (tile st -> slot st&15).
//     - step st: all waves ds_read tile st (2x ds_read_b128 at l*16, conflict-
//       free), lgkmcnt(0) [WAR guard], s_barrier, then wave (st&7) converts its
//       held tile st+8 -> fp8, ds_writes slot (st+8)&15, issues global loads
//       for tile st+16 (8 steps of flight), then everyone: 4 mfma_scale + fmax.
//     - NO __syncthreads in the loop: raw s_barrier doesn't drain vmcnt, so
//       staging loads stay in flight across barriers.
//   d L2 traffic: 256 blocks x 512KB = 134MB (~4us); MFMA total 7.4us -> bound
//   by MFMA + per-step overhead, est ~9-12us.
__launch_bounds__(512, 2)
__global__ void fused_kernel(const float* __restrict__ qm, const float* __restrict__ dm,
                             const float* __restrict__ qs, const float* __restrict__ ds,
                             float* __restrict__ scores, float* __restrict__ svrow) {
    __shared__ __align__(16) unsigned char ring[16 * 2048];  // 32 KB fp8 d-tiles
    __shared__ float smax[8][2][32];                         // 2 KB
    __shared__ float row[BSZ];

    int bid = blockIdx.x;
    int t = threadIdx.x;

    if (bid < 64) {
        // ---- single-vector CE loss rows (verbatim round-2 path, t<256 active) ----
        int b = bid;
        if (t < 256) {
            int c = t >> 2, part = t & 3;
            const float4* qv = (const float4*)(qs + b * DV);
            const float4* dv = (const float4*)(ds + c * DV);
            float acc = 0.f;
            int k0 = part * 64;
#pragma unroll 8
            for (int k = k0; k < k0 + 64; ++k) {
                float4 a = qv[k], bb = dv[k];
                acc += a.x * bb.x + a.y * bb.y + a.z * bb.z + a.w * bb.w;
            }
            acc += __shfl_xor(acc, 1);
            acc += __shfl_xor(acc, 2);
            if (part == 0) row[c] = acc;
        }
        __syncthreads();
        if (t < BSZ) {
            float v = row[t];
            float m = v;
#pragma unroll
            for (int o = 1; o < 64; o <<= 1) m = fmaxf(m, __shfl_xor(m, o));
            float e = expf(v - m);
#pragma unroll
            for (int o = 1; o < 64; o <<= 1) e += __shfl_xor(e, o);
            float lse = m + logf(e);
            if (t == 0) svrow[b] = lse - row[b];
        }
        return;
    }

    // ---- multi-vector path ----
    int mbid = bid - 64;               // 0..255   (64 ≡ 0 mod 8 -> bid&7 == mbid&7)
    int x = mbid & 7, rr = mbid >> 3;
    int c  = x * 8 + (rr & 7);         // XCD x keeps c in [8x,8x+8): 4MB slice L2-resident
    int bg = rr >> 3;                  // 0..3 -> b's bg*16 .. bg*16+15
    int w = t >> 6, l = t & 63;
    int lane16 = l & 15, quad = (l >> 4) & 3;
    int b0 = bg * 16 + w * 2;          // this wave's 2 query rows

    // A-frags straight from global (one-time; no LDS staging, no l*32 conflicts)
    int8v af[2][2];
#pragma unroll
    for (int bi = 0; bi < 2; ++bi)
#pragma unroll
        for (int nt = 0; nt < 2; ++nt) {
            const float4* src = (const float4*)(qm +
                ((size_t)((b0 + bi) * NQ + nt * 16 + lane16)) * DD + quad * 32);
            int dw[8];
#pragma unroll
            for (int j = 0; j < 8; ++j) {
                float4 v = src[j];
                int d0 = __builtin_amdgcn_cvt_pk_fp8_f32(v.x, v.y, 0, false);
                dw[j]  = __builtin_amdgcn_cvt_pk_fp8_f32(v.z, v.w, d0, true);
            }
#pragma unroll
            for (int j = 0; j < 8; ++j) af[bi][nt][j] = dw[j];
        }

    float mx[2][2][4];
#pragma unroll
    for (int bi = 0; bi < 2; ++bi)
#pragma unroll
        for (int nt = 0; nt < 2; ++nt)
#pragma unroll
            for (int r = 0; r < 4; ++r) mx[bi][nt][r] = -1e30f;

    // lane's 128B of d for tile st lives at dbase + st*2048 floats
    const float* dbase = dm + ((size_t)c * NS + lane16) * DD + quad * 32;
    float4 raw[8];

    // prologue: wave w stages tile w into slot w; issues loads for tile w+8
    {
        const float4* p = (const float4*)(dbase + w * 2048);
#pragma unroll
        for (int j = 0; j < 8; ++j) raw[j] = p[j];
        int dw[8];
#pragma unroll
        for (int j = 0; j < 8; ++j) {
            int d0 = __builtin_amdgcn_cvt_pk_fp8_f32(raw[j].x, raw[j].y, 0, false);
            dw[j]  = __builtin_amdgcn_cvt_pk_fp8_f32(raw[j].z, raw[j].w, d0, true);
        }
        *(int4*)(ring + w * 2048 + l * 16)        = make_int4(dw[0], dw[1], dw[2], dw[3]);
        *(int4*)(ring + w * 2048 + 1024 + l * 16) = make_int4(dw[4], dw[5], dw[6], dw[7]);
        const float4* p2 = (const float4*)(dbase + (w + 8) * 2048);
#pragma unroll
        for (int j = 0; j < 8; ++j) raw[j] = p2[j];
    }
    asm volatile("s_waitcnt lgkmcnt(0)" ::: "memory");
    __builtin_amdgcn_sched_barrier(0);
    __builtin_amdgcn_s_barrier();

#pragma unroll 1
    for (int st = 0; st < 64; ++st) {
        // read my B-frag for tile st (conflict-free: lane stride 16B)
        const int4* rp = (const int4*)(ring + (st & 15) * 2048 + l * 16);
        int4 lo = rp[0];
        int4 hi = rp[64];            // +1024 bytes
        int8v bfv;
        bfv[0] = lo.x; bfv[1] = lo.y; bfv[2] = lo.z; bfv[3] = lo.w;
        bfv[4] = hi.x; bfv[5] = hi.y; bfv[6] = hi.z; bfv[7] = hi.w;
        // reads must COMPLETE before anyone's phase-2 write to a ring slot
        asm volatile("s_waitcnt lgkmcnt(0)" ::: "memory");
        __builtin_amdgcn_sched_barrier(0);
        __builtin_amdgcn_s_barrier();

        // phase 2: rotating stager (wave-uniform branch)
        if ((st & 7) == w && st + 8 < 64) {
            int dw[8];
#pragma unroll
            for (int j = 0; j < 8; ++j) {
                int d0 = __builtin_amdgcn_cvt_pk_fp8_f32(raw[j].x, raw[j].y, 0, false);
                dw[j]  = __builtin_amdgcn_cvt_pk_fp8_f32(raw[j].z, raw[j].w, d0, true);
            }
            unsigned s2 = (unsigned)(st + 8) & 15;
            *(int4*)(ring + s2 * 2048 + l * 16)        = make_int4(dw[0], dw[1], dw[2], dw[3]);
            *(int4*)(ring + s2 * 2048 + 1024 + l * 16) = make_int4(dw[4], dw[5], dw[6], dw[7]);
            if (st + 16 < 64) {
                const float4* p = (const float4*)(dbase + (st + 16) * 2048);
#pragma unroll
                for (int j = 0; j < 8; ++j) raw[j] = p[j];
            }
        }

        // compute: 4 mfma_scale (2 b x 2 nt), running per-lane fmax
#pragma unroll
        for (int bi = 0; bi < 2; ++bi)
#pragma unroll
            for (int nt = 0; nt < 2; ++nt) {
                floatx4 acc = __builtin_amdgcn_mfma_scale_f32_16x16x128_f8f6f4(
                    af[bi][nt], bfv, (floatx4){0.f, 0.f, 0.f, 0.f},
                    0, 0, 0, SCALE1, 0, SCALE1);
#pragma unroll
                for (int r = 0; r < 4; ++r)
                    mx[bi][nt][r] = fmaxf(mx[bi][nt][r], acc[r]);
            }
    }

    // ---- end-of-kernel reduction (verified scheme; waves own disjoint b's) ----
#pragma unroll
    for (int bi = 0; bi < 2; ++bi)
#pragma unroll
        for (int nt = 0; nt < 2; ++nt)
#pragma unroll
            for (int r = 0; r < 4; ++r) {
                float v = mx[bi][nt][r];
                v = fmaxf(v, __shfl_xor(v, 1));
                v = fmaxf(v, __shfl_xor(v, 2));
                v = fmaxf(v, __shfl_xor(v, 4));
                v = fmaxf(v, __shfl_xor(v, 8));
                mx[bi][nt][r] = v;
            }
    if (lane16 == 0) {
#pragma unroll
        for (int bi = 0; bi < 2; ++bi)
#pragma unroll
            for (int nt = 0; nt < 2; ++nt)
#pragma unroll
                for (int r = 0; r < 4; ++r)
                    smax[w][bi][nt * 16 + quad * 4 + r] = mx[bi][nt][r];
    }
    __syncthreads();
    {
        int b_idx = t >> 5, n = t & 31;   // 512 threads = 16 b's x 32 q-rows
        float v = smax[b_idx >> 1][b_idx & 1][n];
#pragma unroll
        for (int o = 1; o < 32; o <<= 1) v += __shfl_xor(v, o);
        if (n == 0) scores[(bg * 16 + b_idx) * BSZ + c] = v;
    }
}

// ==================== finisher ====================
__global__ void finish_kernel(const float* __restrict__ scores, const float* __restrict__ svrow,
                              float* __restrict__ out) {
    int t = threadIdx.x;  // 64
    float pos = scores[t * BSZ + t];
    float neg = -1e30f;
    for (int cc = 0; cc < BSZ; ++cc)
        if (cc != t) neg = fmaxf(neg, scores[t * BSZ + cc]);
    float xx = neg - pos;
    float sp = fmaxf(xx, 0.f) + log1pf(expf(-fabsf(xx)));   // stable softplus
    float sv = svrow[t];
#pragma unroll
    for (int o = 1; o < 64; o <<= 1) {
        sp += __shfl_xor(sp, o);
        sv += __shfl_xor(sv, o);
    }
    if (t == 0) out[0] = ALPHA * sv + (1.0f - ALPHA) * (sp * (1.0f / BSZ));
}

// ==================== launch ====================
extern "C" void kernel_launch(void* const* d_in, const int* in_sizes, int n_in,
                              void* d_out, int out_size, void* d_ws, size_t ws_size,
                              hipStream_t stream) {
    const float* q_single = (const float*)d_in[0];
    const float* d_single = (const float*)d_in[1];
    const float* q_multi  = (const float*)d_in[2];
    const float* d_multi  = (const float*)d_in[3];
    float* out = (float*)d_out;

    // ws: scores 16KB | svrow 256B
    float* scores = (float*)d_ws;
    float* svrow  = (float*)((char*)d_ws + 16384);

    fused_kernel<<<320, 512, 0, stream>>>(q_multi, d_multi, q_single, d_single,
                                          scores, svrow);
    finish_kernel<<<1, 64, 0, stream>>>(scores, svrow, out);
}

// Round 4
// 123.997 us; speedup vs baseline: 1.3213x; 1.1274x over previous
//
#include <hip/hip_runtime.h>
#include <hip/hip_bf16.h>
#include <math.h>

// Sizes (fixed by the reference problem)
#define BSZ 64
#define DV  1024
#define NQ  32
#define NS  1024
#define DD  128

#define ALPHA 0.5f

typedef __attribute__((ext_vector_type(8))) int   int8v;    // 32B fp8 MFMA A/B frag (8 VGPR)
typedef __attribute__((ext_vector_type(4))) float floatx4;  // MFMA C/D frag
#define SCALE1 127      // e8m0 byte 0x7F = 2^0 = 1.0

// ==================== prep ====================
// blocks 0..511  : d_multi fp32 -> fp8(e4m3), swizzled to 16x16x128 B-frag chunks
//                  chunk ch=(c,st): lane l holds d[c][st*16+(l&15)][((l>>4)&3)*32 .. +32] (32B)
//                  (512 blocks x 2 chunks/wave: 2.3 blocks/CU to saturate HBM; round-0
//                   used 256x4 = 1.3/CU)
// blocks 512..519: q_multi fp32 -> fp8, A-frag chunks: (b,nt): lane l holds
//                  q[b][nt*16+(l&15)][((l>>4)&3)*32 .. +32]
// blocks 520..583: single-vector CE loss rows (exact fp32)
__global__ void prep_kernel(const float* __restrict__ qm, const float* __restrict__ dm,
                            const float* __restrict__ qs, const float* __restrict__ ds,
                            unsigned char* __restrict__ qb8, unsigned char* __restrict__ db8,
                            float* __restrict__ svrow) {
    __shared__ float row[BSZ];
    int bid = blockIdx.x, t = threadIdx.x;
    int w = t >> 6, l = t & 63;
    int lane16 = l & 15, quad = (l >> 4) & 3;

    auto cvt_chunk = [&](const float* src, unsigned char* dst) {
        // src: 32 contiguous floats for this lane; dst: 32 bytes at lane slot
        int dw[8];
#pragma unroll
        for (int j = 0; j < 8; ++j) {
            float4 v = ((const float4*)src)[j];
            int d0 = __builtin_amdgcn_cvt_pk_fp8_f32(v.x, v.y, 0, false);
            dw[j]  = __builtin_amdgcn_cvt_pk_fp8_f32(v.z, v.w, d0, true);
        }
        ((int4*)dst)[0] = make_int4(dw[0], dw[1], dw[2], dw[3]);
        ((int4*)dst)[1] = make_int4(dw[4], dw[5], dw[6], dw[7]);
    };

    if (bid < 512) {
        int gw = bid * 4 + w;                 // 2048 waves
#pragma unroll
        for (int it = 0; it < 2; ++it) {
            int ch = gw + it * 2048;          // 4096 chunks (c*64+st)
            int c = ch >> 6, st = ch & 63;
            const float* src = dm + ((size_t)(c * NS + st * 16 + lane16)) * DD + quad * 32;
            cvt_chunk(src, db8 + (size_t)ch * 2048 + l * 32);
        }
    } else if (bid < 520) {
        int gw = (bid - 512) * 4 + w;         // 32 waves
#pragma unroll
        for (int it = 0; it < 4; ++it) {
            int ch = gw * 4 + it;             // 128 chunks (b*2+nt)
            int b = ch >> 1, nt = ch & 1;
            const float* src = qm + ((size_t)(b * NQ + nt * 16 + lane16)) * DD + quad * 32;
            cvt_chunk(src, qb8 + (size_t)ch * 2048 + l * 32);
        }
    } else {
        int b = bid - 520;                    // 0..63
        int c = t >> 2, part = t & 3;
        const float4* qv = (const float4*)(qs + b * DV);
        const float4* dv = (const float4*)(ds + c * DV);
        float acc = 0.f;
        int k0 = part * 64;
#pragma unroll 8
        for (int k = k0; k < k0 + 64; ++k) {
            float4 a = qv[k], bb = dv[k];
            acc += a.x * bb.x + a.y * bb.y + a.z * bb.z + a.w * bb.w;
        }
        acc += __shfl_xor(acc, 1);
        acc += __shfl_xor(acc, 2);
        if (part == 0) row[c] = acc;
        __syncthreads();
        if (t < BSZ) {
            float v = row[t];
            float m = v;
#pragma unroll
            for (int o = 1; o < 64; o <<= 1) m = fmaxf(m, __shfl_xor(m, o));
            float e = expf(v - m);
#pragma unroll
            for (int o = 1; o < 64; o <<= 1) e += __shfl_xor(e, o);
            float lse = m + logf(e);
            if (t == 0) svrow[b] = lse - row[b];
        }
    }
}

// ==================== multi (MX-fp8, K=128 in one MFMA) ====================
// block = (bg of 4 b's, c); wave w owns s-tiles st = w+4i. One mfma_scale per
// (bi,nt,st) computes the full 16x16 score tile over D=128. LDS-free main loop,
// register double-buffered B, running max in regs, single end reduction.
// launch_bounds(256,3): 3 blocks/CU (vs round-0's 2) = 3 waves/SIMD to fill
// B-load latency gaps; VGPR cap 170 > ~150 needed -> no spill expected.
__launch_bounds__(256, 3)
__global__ void multi_kernel(const unsigned char* __restrict__ qb8,
                             const unsigned char* __restrict__ db8,
                             float* __restrict__ scores) {
    int bid = blockIdx.x;            // 0..1023
    int x = bid & 7, rr = bid >> 3;
    int c  = x * 8 + (rr & 7);       // XCD x keeps c in [8x,8x+8): 1MB of db8 -> L2-resident
    int bg = rr >> 3;                // 0..15
    int t  = threadIdx.x;
    int w  = t >> 6;
    int l  = t & 63;
    int lane16 = l & 15;
    int quad   = (l >> 4) & 3;

    __shared__ float smax[4][4][NQ];

    // A-frags (q), loaded once, coalesced (lane l at +l*32B within 2KB chunk)
    int8v af[4][2];
#pragma unroll
    for (int bi = 0; bi < 4; ++bi)
#pragma unroll
        for (int nt = 0; nt < 2; ++nt)
            af[bi][nt] = *(const int8v*)(qb8 +
                (size_t)(((bg * 4 + bi) * 2 + nt) * 2048) + l * 32);

    float mx[4][2][4];
#pragma unroll
    for (int bi = 0; bi < 4; ++bi)
#pragma unroll
        for (int nt = 0; nt < 2; ++nt)
#pragma unroll
            for (int r = 0; r < 4; ++r) mx[bi][nt][r] = -1e30f;

    int8v bf[2];
    auto loadb = [&](int which, int st) {
        bf[which] = *(const int8v*)(db8 + (size_t)((c * 64 + st) * 2048) + l * 32);
    };

    loadb(0, w);
#pragma unroll
    for (int i = 0; i < 16; ++i) {
        if (i < 15) loadb((i + 1) & 1, w + (i + 1) * 4);
        int8v B = bf[i & 1];
#pragma unroll
        for (int bi = 0; bi < 4; ++bi)
#pragma unroll
            for (int nt = 0; nt < 2; ++nt) {
                floatx4 acc = __builtin_amdgcn_mfma_scale_f32_16x16x128_f8f6f4(
                    af[bi][nt], B, (floatx4){0.f, 0.f, 0.f, 0.f},
                    0, 0,                 // cbsz=fp8(e4m3), blgp=fp8(e4m3)
                    0, SCALE1,            // scale_a: opsel 0, byte 0x7F = 1.0
                    0, SCALE1);           // scale_b
                // C/D: col(s)=lane&15, row(n)=quad*4+r -> independent running fmax
#pragma unroll
                for (int r = 0; r < 4; ++r)
                    mx[bi][nt][r] = fmaxf(mx[bi][nt][r], acc[r]);
            }
    }

    // ---- single end-of-kernel reduction (round-1/5 verified path) ----
#pragma unroll
    for (int bi = 0; bi < 4; ++bi)
#pragma unroll
        for (int nt = 0; nt < 2; ++nt)
#pragma unroll
            for (int r = 0; r < 4; ++r) {
                float v = mx[bi][nt][r];
                v = fmaxf(v, __shfl_xor(v, 1));
                v = fmaxf(v, __shfl_xor(v, 2));
                v = fmaxf(v, __shfl_xor(v, 4));
                v = fmaxf(v, __shfl_xor(v, 8));
                mx[bi][nt][r] = v;
            }
    if (lane16 == 0) {
#pragma unroll
        for (int bi = 0; bi < 4; ++bi)
#pragma unroll
            for (int nt = 0; nt < 2; ++nt)
#pragma unroll
                for (int r = 0; r < 4; ++r)
                    smax[w][bi][nt * 16 + quad * 4 + r] = mx[bi][nt][r];
    }
    __syncthreads();
    if (t < 4 * NQ) {
        int bi = t >> 5, n = t & 31;
        float v = fmaxf(fmaxf(smax[0][bi][n], smax[1][bi][n]),
                        fmaxf(smax[2][bi][n], smax[3][bi][n]));
#pragma unroll
        for (int o = 1; o < 32; o <<= 1) v += __shfl_xor(v, o);
        if (n == 0) scores[(bg * 4 + bi) * BSZ + c] = v;
    }
}

// ==================== finisher ====================
__global__ void finish_kernel(const float* __restrict__ scores, const float* __restrict__ svrow,
                              float* __restrict__ out) {
    int t = threadIdx.x;  // 64
    float pos = scores[t * BSZ + t];
    float neg = -1e30f;
    for (int cc = 0; cc < BSZ; ++cc)
        if (cc != t) neg = fmaxf(neg, scores[t * BSZ + cc]);
    float xx = neg - pos;
    float sp = fmaxf(xx, 0.f) + log1pf(expf(-fabsf(xx)));   // stable softplus
    float sv = svrow[t];
#pragma unroll
    for (int o = 1; o < 64; o <<= 1) {
        sp += __shfl_xor(sp, o);
        sv += __shfl_xor(sv, o);
    }
    if (t == 0) out[0] = ALPHA * sv + (1.0f - ALPHA) * (sp * (1.0f / BSZ));
}

// ==================== launch ====================
extern "C" void kernel_launch(void* const* d_in, const int* in_sizes, int n_in,
                              void* d_out, int out_size, void* d_ws, size_t ws_size,
                              hipStream_t stream) {
    const float* q_single = (const float*)d_in[0];
    const float* d_single = (const float*)d_in[1];
    const float* q_multi  = (const float*)d_in[2];
    const float* d_multi  = (const float*)d_in[3];
    float* out = (float*)d_out;

    // ws: qb8 256KB | db8 8MB | scores 16KB | svrow 256B
    unsigned char* qb8 = (unsigned char*)d_ws;
    unsigned char* db8 = (unsigned char*)d_ws + 262144;
    float* scores      = (float*)((char*)d_ws + 262144 + 8388608);
    float* svrow       = (float*)((char*)d_ws + 262144 + 8388608 + 16384);

    prep_kernel<<<584, 256, 0, stream>>>(q_multi, d_multi, q_single, d_single,
                                         qb8, db8, svrow);
    multi_kernel<<<1024, 256, 0, stream>>>(qb8, db8, scores);
    finish_kernel<<<1, 64, 0, stream>>>(scores, svrow, out);
}